// Round 5
// baseline (177.262 us; speedup 1.0000x reference)
//
#include <hip/hip_runtime.h>
#include <hip/hip_cooperative_groups.h>

namespace cg = cooperative_groups;

// ---------------------------------------------------------------------------
// Output depends ONLY on positions[0:64]. ~25 MFLOP total.
//
// R5: ONE cooperative kernel (29 blocks x 256), 4 grid.sync()s.
//  roles: b0 backbone | b1-8 gf | b9-16 tbar | b17-24 agg | b25-28 heads+out
//  ALL weight slices async-staged into LDS at kernel entry (overlapped with
//  phase 0), so the dependent chain pays only compute + syncs.
// Fallback: if cooperative launch fails, run the R4 six-kernel path (proven
// absmax 0.0) in the same kernel_launch call.
//
// BIT-EXACTNESS: harness demands bit-exact bf16. Every per-output
// accumulation below is the VERBATIM expression structure from R4 (absmax
// 0.0). Only load sources / block ownership changed. Do not reassociate.
// ---------------------------------------------------------------------------

__device__ __forceinline__ void async_cp16(const float* g, float* l) {
    __builtin_amdgcn_global_load_lds(
        (const __attribute__((address_space(1))) void*)g,
        (__attribute__((address_space(3))) void*)l, 16, 0, 0);
}
// contiguous: nfloats multiple of 256; 1 inst moves 256 floats (64 lanes x 16B)
__device__ __forceinline__ void stage_contig(const float* g, float* l, int nfloats, int tid) {
    const int lane = tid & 63, wv = tid >> 6;
    const int ninst = nfloats >> 8;
    for (int i = wv; i < ninst; i += 4)
        async_cp16(g + i*256 + lane*4, l + i*256);
}
// 32-col slice of row-major [nrows][ld] at col j0 -> LDS [r][32]
__device__ __forceinline__ void stage_slice32(const float* g, float* l, int ld, int j0, int nrows, int tid) {
    const int lane = tid & 63, wv = tid >> 6;
    const int r = lane >> 3, c4 = (lane & 7) << 2;
    const int ninst = nrows >> 3;
    for (int i = wv; i < ninst; i += 4)
        async_cp16(g + (i*8 + r)*ld + j0 + c4, l + i*256);
}

#define COOP_SMEM_BYTES 131072   // 32768 floats (heads role: Wh1[k] = 128 KB)

__global__ __launch_bounds__(256) void fused_coop(
    const float* __restrict__ positions, const float* __restrict__ grid_pts,
    const float* __restrict__ W1, const float* __restrict__ b1,
    const float* __restrict__ W2, const float* __restrict__ b2,
    const float* __restrict__ W3, const float* __restrict__ b3,
    const float* __restrict__ Wn1, const float* __restrict__ bn1,
    const float* __restrict__ Wn2, const float* __restrict__ bn2,
    const float* __restrict__ Wh1, const float* __restrict__ bh1,
    const float* __restrict__ Wh2, const float* __restrict__ bh2,
    float* __restrict__ h2g_ws, int* __restrict__ win_ws,
    float* __restrict__ gf_ws, float* __restrict__ tbar_ws,
    float* __restrict__ agg_ws, float* __restrict__ out)
{
    extern __shared__ float smem[];
    __shared__ float pos_s[192], grid_s[192], w1_s[192], b1_s[64];
    __shared__ int   idx_s[64], win_s[64];
    __shared__ __align__(16) float tbar_s[256];   // agg role
    __shared__ __align__(16) float agg_s[256];    // heads role
    __shared__ __align__(16) float h1h_s[128];    // heads role
    __shared__ __align__(16) float wh2_s[128];    // heads role

    const int tid = threadIdx.x;
    const int bid = blockIdx.x;
    cg::grid_group gg = cg::this_grid();

    // ---------------- entry: per-role async staging + early bias loads -----
    float bb2 = 0.f, bb3 = 0.f, bbn1 = 0.f, bbn2 = 0.f, bbh1 = 0.f, bbh2 = 0.f;

    if (bid == 0) {
        stage_contig(W2, smem, 64*128, tid);                      // 32 KB
        if (tid < 192) { pos_s[tid] = positions[tid]; grid_s[tid] = grid_pts[tid]; w1_s[tid] = W1[tid]; }
        if (tid >= 192) b1_s[tid - 192] = b1[tid - 192];
        bb2 = b2[tid & 127];
    } else if (bid <= 8) {            // gf: cols [j0,j0+32) of W3
        const int j0 = (bid - 1) * 32;
        stage_slice32(W3, smem, 256, j0, 128, tid);               // 16 KB
        bb3 = b3[j0 + (tid & 31)];
    } else if (bid <= 16) {           // tbar: cols [j0,j0+32) of Wn1
        const int j0 = (bid - 9) * 32;
        stage_slice32(Wn1, smem, 256, j0, 256, tid);              // 32 KB
        bbn1 = bn1[j0 + (tid & 31)];
    } else if (bid <= 24) {           // agg: cols [c0,c0+32) of Wn2
        const int c0 = (bid - 17) * 32;
        stage_slice32(Wn2, smem, 256, c0, 256, tid);              // 32 KB
        bbn2 = bn2[c0 + (tid & 31)];
    } else {                          // heads: Wh1[k] whole
        const int k = bid - 25;
        stage_contig(Wh1 + k*256*128, smem, 256*128, tid);        // 128 KB
        if (tid < 128) { bbh1 = bh1[k*128 + tid]; wh2_s[tid] = Wh2[k*128 + tid]; }
        bbh2 = bh2[k];
    }

    // ---------------- phase 0: backbone (b0 only) --------------------------
    if (bid == 0) {
        float* w2_s = smem;            // 64*128
        float* h1_s = smem + 8192;     // 64*64
        __syncthreads();               // drains W2 staging + pos/grid writes

        if (tid < 64) {                // verbatim argmin
            const float px = pos_s[tid*3], py = pos_s[tid*3+1], pz = pos_s[tid*3+2];
            float best = 3.4e38f; int bi = 0;
            for (int g = 0; g < 64; ++g) {
                const float dx = px - grid_s[g*3];
                const float dy = py - grid_s[g*3+1];
                const float dz = pz - grid_s[g*3+2];
                const float d2 = dx*dx + dy*dy + dz*dz;
                if (d2 < best) { best = d2; bi = g; }
            }
            idx_s[tid] = bi;
        }
        __syncthreads();
        if (tid < 64) {                // verbatim winner rule
            int m = -1;
            for (int i = 0; i < 64; ++i) if (idx_s[i] == tid) m = i;
            win_s[tid] = m;
            win_ws[tid] = m;
        }
        __syncthreads();

        #pragma unroll                 // verbatim h1 (all 64 slots)
        for (int u = 0; u < 16; ++u) {
            const int e = tid + u*256;
            const int t = e >> 6, kk = e & 63;
            int r = win_s[t]; if (r < 0) r = 0;
            const float acc = b1_s[kk] + pos_s[r*3]*w1_s[kk] + pos_s[r*3+1]*w1_s[64+kk]
                                       + pos_s[r*3+2]*w1_s[128+kk];
            h1_s[t*64 + kk] = fmaxf(acc, 0.f);
        }
        __syncthreads();

        {   // verbatim h2 stage
            const int d = tid & 127, t0 = tid >> 7;
            for (int bp = 0; bp < 8; ++bp) {
                float acc[4];
                #pragma unroll
                for (int m = 0; m < 4; ++m) acc[m] = bb2;
                for (int kc = 0; kc < 64; kc += 16) {
                    float w[16];
                    #pragma unroll
                    for (int u = 0; u < 16; ++u) w[u] = w2_s[(kc+u)*128 + d];
                    #pragma unroll
                    for (int u = 0; u < 16; u += 4) {
                        #pragma unroll
                        for (int m = 0; m < 4; ++m) {
                            const float4 h4 = *(const float4*)&h1_s[(bp*8 + t0 + 2*m)*64 + kc + u];
                            acc[m] += h4.x*w[u] + h4.y*w[u+1] + h4.z*w[u+2] + h4.w*w[u+3];
                        }
                    }
                }
                #pragma unroll
                for (int m = 0; m < 4; ++m)
                    h2g_ws[(bp*8 + t0 + 2*m)*128 + d] = fmaxf(acc[m], 0.f);
            }
        }
    }

    gg.sync();   // ---- h2g_ws, win_ws visible grid-wide ----

    // ---------------- phase 1: gf (b1..b8) ---------------------------------
    if (bid >= 1 && bid <= 8) {
        const int j0 = (bid - 1) * 32;
        float* w3_s = smem;            // 128*32
        float* h2_s = smem + 4096;     // 64*128
        stage_contig(h2g_ws, h2_s, 64*128, tid);
        if (tid < 64) win_s[tid] = win_ws[tid];
        __syncthreads();               // ONE drain

        const int jl = tid & 31, g = tid >> 5;
        float acc[8];                  // verbatim gf stage
        #pragma unroll
        for (int t = 0; t < 8; ++t) acc[t] = 0.f;
        for (int dc = 0; dc < 128; dc += 16) {
            float w[16];
            #pragma unroll
            for (int u = 0; u < 16; ++u) w[u] = w3_s[(dc+u)*32 + jl];
            #pragma unroll
            for (int u = 0; u < 16; u += 4) {
                #pragma unroll
                for (int t = 0; t < 8; ++t) {
                    const float4 h4 = *(const float4*)&h2_s[(g*8 + t)*128 + dc + u];
                    acc[t] += h4.x*w[u] + h4.y*w[u+1] + h4.z*w[u+2] + h4.w*w[u+3];
                }
            }
        }
        #pragma unroll
        for (int t = 0; t < 8; ++t)
            gf_ws[(g*8 + t)*256 + j0 + jl] = (win_s[g*8 + t] >= 0) ? (acc[t] + bb3) : 0.f;
    }

    gg.sync();   // ---- gf_ws visible ----

    // ---------------- phase 2: tbar (b9..b16) ------------------------------
    if (bid >= 9 && bid <= 16) {
        const int j0 = (bid - 9) * 32;
        float* wn1_s = smem;            // 256*32
        float* gfs   = smem + 8192;     // 64*256
        float* r_s   = smem + 24576;    // 64*32
        stage_contig(gf_ws, gfs, 64*256, tid);
        __syncthreads();               // ONE drain

        const int jl = tid & 31, t = tid >> 5;
        float acc[8];                  // row bg*8+t per bg; verbatim per-row order
        #pragma unroll
        for (int bg = 0; bg < 8; ++bg) acc[bg] = bbn1;
        for (int cc = 0; cc < 256; cc += 32) {
            float w[32];
            #pragma unroll
            for (int u = 0; u < 32; ++u) w[u] = wn1_s[(cc+u)*32 + jl];
            #pragma unroll
            for (int u = 0; u < 32; u += 4) {
                #pragma unroll
                for (int bg = 0; bg < 8; ++bg) {
                    const float4 g4 = *(const float4*)&gfs[(bg*8 + t)*256 + cc + u];
                    acc[bg] += g4.x*w[u] + g4.y*w[u+1] + g4.z*w[u+2] + g4.w*w[u+3];
                }
            }
        }
        #pragma unroll
        for (int bg = 0; bg < 8; ++bg)
            r_s[(bg*8 + t)*32 + jl] = fmaxf(acc[bg], 0.f);
        __syncthreads();
        if (t == 0) {                  // two-level sum: verbatim R4 k2 ps then k3 tb
            float tb = 0.f;
            #pragma unroll
            for (int bg = 0; bg < 8; ++bg) {
                float ps = 0.f;
                #pragma unroll
                for (int tt = 0; tt < 8; ++tt) ps += r_s[(bg*8 + tt)*32 + jl];
                tb += ps;
            }
            tbar_ws[j0 + jl] = tb * (1.f/64.f);
        }
    }

    gg.sync();   // ---- tbar_ws visible ----

    // ---------------- phase 3: agg (b17..b24) ------------------------------
    if (bid >= 17 && bid <= 24) {
        const int c0 = (bid - 17) * 32;
        float* wn2_s = smem;            // 256*32
        tbar_s[tid] = tbar_ws[tid];
        __syncthreads();

        if (tid < 32) {                // verbatim agg chunks
            float acc = bbn2;
            for (int jc = 0; jc < 256; jc += 32) {
                float w[32];
                #pragma unroll
                for (int u = 0; u < 32; ++u) w[u] = wn2_s[(jc+u)*32 + tid];
                #pragma unroll
                for (int u = 0; u < 32; u += 4) {
                    const float4 t4 = *(const float4*)&tbar_s[jc + u];
                    acc += t4.x*w[u] + t4.y*w[u+1] + t4.z*w[u+2] + t4.w*w[u+3];
                }
            }
            agg_ws[c0 + tid] = acc;
        }
    }

    gg.sync();   // ---- agg_ws visible ----

    // ---------------- phase 4: heads + out (b25..b28) ----------------------
    if (bid >= 25) {
        const int k = bid - 25;
        float* wh1_s = smem;            // 256*128
        agg_s[tid] = agg_ws[tid];
        __syncthreads();

        if (tid < 128) {               // verbatim head chunks (full-width slice)
            const int d = tid;
            float acc = bbh1;
            for (int cc = 0; cc < 256; cc += 16) {
                float wa[16];
                #pragma unroll
                for (int u = 0; u < 16; ++u) wa[u] = wh1_s[(cc+u)*128 + d];
                #pragma unroll
                for (int u = 0; u < 16; u += 4) {
                    const float4 a4 = *(const float4*)&agg_s[cc + u];
                    acc += a4.x*wa[u] + a4.y*wa[u+1] + a4.z*wa[u+2] + a4.w*wa[u+3];
                }
            }
            h1h_s[d] = fmaxf(acc, 0.f);
        }
        __syncthreads();
        if (tid == 0) {                // verbatim strictly-sequential final dot
            float acc = bbh2;
            for (int d = 0; d < 128; ++d) acc += h1h_s[d] * wh2_s[d];
            out[k] = acc;
        }
    }
}

// ===========================================================================
// R4 fallback path (proven absmax 0.0) — used only if cooperative launch fails
// ===========================================================================

__global__ __launch_bounds__(256) void k0_backbone(
    const float* __restrict__ positions, const float* __restrict__ grid,
    const float* __restrict__ W1, const float* __restrict__ b1,
    const float* __restrict__ W2, const float* __restrict__ b2,
    float* __restrict__ h2g_ws, int* __restrict__ win_ws)
{
    __shared__ __align__(16) float w2_s[64*128];
    __shared__ __align__(16) float h1_s[64][64];
    __shared__ float pos_s[192], grid_s[192], w1_s[192], b1_s[64];
    __shared__ int idx_s[64], win_s[64];

    const int tid = threadIdx.x;
    stage_contig(W2, w2_s, 64*128, tid);

    if (tid < 192) { pos_s[tid] = positions[tid]; grid_s[tid] = grid[tid]; w1_s[tid] = W1[tid]; }
    if (tid >= 192) b1_s[tid - 192] = b1[tid - 192];
    const float bb2 = b2[tid & 127];
    __syncthreads();

    if (tid < 64) {
        const float px = pos_s[tid*3], py = pos_s[tid*3+1], pz = pos_s[tid*3+2];
        float best = 3.4e38f; int bi = 0;
        for (int g = 0; g < 64; ++g) {
            const float dx = px - grid_s[g*3];
            const float dy = py - grid_s[g*3+1];
            const float dz = pz - grid_s[g*3+2];
            const float d2 = dx*dx + dy*dy + dz*dz;
            if (d2 < best) { best = d2; bi = g; }
        }
        idx_s[tid] = bi;
    }
    __syncthreads();
    if (tid < 64) {
        int m = -1;
        for (int i = 0; i < 64; ++i) if (idx_s[i] == tid) m = i;
        win_s[tid] = m;
        win_ws[tid] = m;
    }
    __syncthreads();

    #pragma unroll
    for (int u = 0; u < 16; ++u) {
        const int e = tid + u*256;
        const int t = e >> 6, k = e & 63;
        int r = win_s[t]; if (r < 0) r = 0;
        const float acc = b1_s[k] + pos_s[r*3]*w1_s[k] + pos_s[r*3+1]*w1_s[64+k]
                                  + pos_s[r*3+2]*w1_s[128+k];
        h1_s[t][k] = fmaxf(acc, 0.f);
    }
    __syncthreads();

    {
        const int d = tid & 127, t0 = tid >> 7;
        for (int bp = 0; bp < 8; ++bp) {
            float acc[4];
            #pragma unroll
            for (int m = 0; m < 4; ++m) acc[m] = bb2;
            for (int kc = 0; kc < 64; kc += 16) {
                float w[16];
                #pragma unroll
                for (int u = 0; u < 16; ++u) w[u] = w2_s[(kc+u)*128 + d];
                #pragma unroll
                for (int u = 0; u < 16; u += 4) {
                    #pragma unroll
                    for (int m = 0; m < 4; ++m) {
                        const float4 h4 = *(const float4*)&h1_s[bp*8 + t0 + 2*m][kc + u];
                        acc[m] += h4.x*w[u] + h4.y*w[u+1] + h4.z*w[u+2] + h4.w*w[u+3];
                    }
                }
            }
            #pragma unroll
            for (int m = 0; m < 4; ++m)
                h2g_ws[(bp*8 + t0 + 2*m)*128 + d] = fmaxf(acc[m], 0.f);
        }
    }
}

__global__ __launch_bounds__(256) void k1_gf(
    const float* __restrict__ W3, const float* __restrict__ b3,
    const float* __restrict__ h2g_ws, const int* __restrict__ win_ws,
    float* __restrict__ gf_ws)
{
    __shared__ __align__(16) float w3_s[128*32];
    __shared__ __align__(16) float h2_s[64*128];
    __shared__ int win_s[64];

    const int tid = threadIdx.x;
    const int j0  = blockIdx.x * 32;
    stage_slice32(W3, w3_s, 256, j0, 128, tid);
    stage_contig(h2g_ws, h2_s, 64*128, tid);

    const int jl = tid & 31, g = tid >> 5;
    const int j  = j0 + jl;
    const float bb = b3[j];
    if (tid < 64) win_s[tid] = win_ws[tid];
    __syncthreads();

    float acc[8];
    #pragma unroll
    for (int t = 0; t < 8; ++t) acc[t] = 0.f;
    for (int dc = 0; dc < 128; dc += 16) {
        float w[16];
        #pragma unroll
        for (int u = 0; u < 16; ++u) w[u] = w3_s[(dc+u)*32 + jl];
        #pragma unroll
        for (int u = 0; u < 16; u += 4) {
            #pragma unroll
            for (int t = 0; t < 8; ++t) {
                const float4 h4 = *(const float4*)&h2_s[(g*8 + t)*128 + dc + u];
                acc[t] += h4.x*w[u] + h4.y*w[u+1] + h4.z*w[u+2] + h4.w*w[u+3];
            }
        }
    }
    #pragma unroll
    for (int t = 0; t < 8; ++t)
        gf_ws[(g*8 + t)*256 + j] = (win_s[g*8 + t] >= 0) ? (acc[t] + bb) : 0.f;
}

__global__ __launch_bounds__(256) void k2_tpart(
    const float* __restrict__ Wn1, const float* __restrict__ bn1,
    const float* __restrict__ gf_ws, float* __restrict__ tpart_ws)
{
    __shared__ __align__(16) float wn1_s[256*32];
    __shared__ __align__(16) float gf_s[8*256];
    __shared__ float r_s[256];

    const int tid = threadIdx.x;
    const int bg  = blockIdx.x >> 3;
    const int j0  = (blockIdx.x & 7) * 32;
    stage_slice32(Wn1, wn1_s, 256, j0, 256, tid);
    stage_contig(gf_ws + bg*8*256, gf_s, 8*256, tid);

    const int jl = tid & 31, t = tid >> 5;
    const float bb = bn1[j0 + jl];
    __syncthreads();

    float acc = bb;
    for (int cc = 0; cc < 256; cc += 32) {
        float w[32];
        #pragma unroll
        for (int u = 0; u < 32; ++u) w[u] = wn1_s[(cc+u)*32 + jl];
        #pragma unroll
        for (int u = 0; u < 32; u += 4) {
            const float4 g4 = *(const float4*)&gf_s[t*256 + cc + u];
            acc += g4.x*w[u] + g4.y*w[u+1] + g4.z*w[u+2] + g4.w*w[u+3];
        }
    }
    r_s[tid] = fmaxf(acc, 0.f);
    __syncthreads();
    if (t == 0) {
        float ps = 0.f;
        #pragma unroll
        for (int tt = 0; tt < 8; ++tt) ps += r_s[tt*32 + jl];
        tpart_ws[bg*256 + j0 + jl] = ps;
    }
}

__global__ __launch_bounds__(256) void k3_agg(
    const float* __restrict__ Wn2, const float* __restrict__ bn2,
    const float* __restrict__ tpart_ws, float* __restrict__ agg_ws)
{
    __shared__ __align__(16) float wn2_s[256*32];
    __shared__ __align__(16) float tp_s[8*256];
    __shared__ __align__(16) float tbars[256];

    const int tid = threadIdx.x;
    const int c0  = blockIdx.x * 32;
    stage_slice32(Wn2, wn2_s, 256, c0, 256, tid);
    stage_contig(tpart_ws, tp_s, 8*256, tid);

    const float bb = (tid < 32) ? bn2[c0 + tid] : 0.f;
    __syncthreads();

    {
        float tb = 0.f;
        #pragma unroll
        for (int q = 0; q < 8; ++q) tb += tp_s[q*256 + tid];
        tbars[tid] = tb * (1.f/64.f);
    }
    __syncthreads();

    if (tid < 32) {
        float acc = bb;
        for (int jc = 0; jc < 256; jc += 32) {
            float w[32];
            #pragma unroll
            for (int u = 0; u < 32; ++u) w[u] = wn2_s[(jc+u)*32 + tid];
            #pragma unroll
            for (int u = 0; u < 32; u += 4) {
                const float4 t4 = *(const float4*)&tbars[jc + u];
                acc += t4.x*w[u] + t4.y*w[u+1] + t4.z*w[u+2] + t4.w*w[u+3];
            }
        }
        agg_ws[c0 + tid] = acc;
    }
}

__global__ __launch_bounds__(256) void k4_heads(
    const float* __restrict__ Wh1, const float* __restrict__ bh1,
    const float* __restrict__ agg_ws, float* __restrict__ h1h_ws)
{
    __shared__ __align__(16) float wh1_s[256*32];
    __shared__ __align__(16) float aggs[256];

    const int tid = threadIdx.x;
    const int k   = blockIdx.x >> 2;
    const int d0  = (blockIdx.x & 3) * 32;
    stage_slice32(Wh1 + k*256*128, wh1_s, 128, d0, 256, tid);
    stage_contig(agg_ws, aggs, 256, tid);

    const float bia = (tid < 32) ? bh1[k*128 + d0 + tid] : 0.f;
    __syncthreads();

    if (tid < 32) {
        float acc = bia;
        for (int cc = 0; cc < 256; cc += 16) {
            float wa[16];
            #pragma unroll
            for (int u = 0; u < 16; ++u) wa[u] = wh1_s[(cc+u)*32 + tid];
            #pragma unroll
            for (int u = 0; u < 16; u += 4) {
                const float4 a4 = *(const float4*)&aggs[cc + u];
                acc += a4.x*wa[u] + a4.y*wa[u+1] + a4.z*wa[u+2] + a4.w*wa[u+3];
            }
        }
        h1h_ws[k*128 + d0 + tid] = fmaxf(acc, 0.f);
    }
}

__global__ __launch_bounds__(256) void k5_out(
    const float* __restrict__ Wh2, const float* __restrict__ bh2,
    const float* __restrict__ h1h_ws, float* __restrict__ out)
{
    __shared__ __align__(16) float h1hs[512];
    __shared__ __align__(16) float wh2s[512];
    const int tid = threadIdx.x;
    stage_contig(h1h_ws, h1hs, 512, tid);
    stage_contig(Wh2,    wh2s, 512, tid);
    const float bb = (tid < 4) ? bh2[tid] : 0.f;
    __syncthreads();

    if (tid < 4) {
        float acc = bb;
        for (int d = 0; d < 128; ++d) acc += h1hs[tid*128 + d] * wh2s[tid*128 + d];
        out[tid] = acc;
    }
}

extern "C" void kernel_launch(void* const* d_in, const int* in_sizes, int n_in,
                              void* d_out, int out_size, void* d_ws, size_t ws_size,
                              hipStream_t stream) {
    const float* positions = (const float*)d_in[0];
    const float* grid      = (const float*)d_in[1];
    const float* W1  = (const float*)d_in[2];
    const float* b1  = (const float*)d_in[3];
    const float* W2  = (const float*)d_in[4];
    const float* b2  = (const float*)d_in[5];
    const float* W3  = (const float*)d_in[6];
    const float* b3  = (const float*)d_in[7];
    const float* Wn1 = (const float*)d_in[8];
    const float* bn1 = (const float*)d_in[9];
    const float* Wn2 = (const float*)d_in[10];
    const float* bn2 = (const float*)d_in[11];
    const float* Wh1 = (const float*)d_in[12];
    const float* bh1 = (const float*)d_in[13];
    const float* Wh2 = (const float*)d_in[14];
    const float* bh2 = (const float*)d_in[15];
    float* out = (float*)d_out;

    char* ws = (char*)d_ws;
    float* h2g_ws   = (float*)(ws + 0);         // 64*128 f = 32 KB
    int*   win_ws   = (int*)  (ws + 32768);     // 64 i32
    float* gf_ws    = (float*)(ws + 36864);     // 64*256 f = 64 KB
    float* tpart_ws = (float*)(ws + 102400);    // 8*256 f (fallback)
    float* agg_ws   = (float*)(ws + 110592);    // 256 f
    float* h1h_ws   = (float*)(ws + 111616);    // 512 f (fallback)
    float* tbar_ws  = (float*)(ws + 120832);    // 256 f (coop)

    static int smem_attr_set = 0;
    if (!smem_attr_set) {   // idempotent, not a stream op (capture-safe)
        (void)hipFuncSetAttribute((const void*)fused_coop,
                                  hipFuncAttributeMaxDynamicSharedMemorySize,
                                  COOP_SMEM_BYTES);
        smem_attr_set = 1;
    }

    void* args[] = {
        (void*)&positions, (void*)&grid, (void*)&W1, (void*)&b1, (void*)&W2,
        (void*)&b2, (void*)&W3, (void*)&b3, (void*)&Wn1, (void*)&bn1,
        (void*)&Wn2, (void*)&bn2, (void*)&Wh1, (void*)&bh1, (void*)&Wh2,
        (void*)&bh2, (void*)&h2g_ws, (void*)&win_ws, (void*)&gf_ws,
        (void*)&tbar_ws, (void*)&agg_ws, (void*)&out };

    hipError_t e = hipLaunchCooperativeKernel((const void*)fused_coop,
                                              dim3(29), dim3(256), args,
                                              COOP_SMEM_BYTES, stream);
    if (e != hipSuccess) {
        (void)hipGetLastError();   // clear sticky error, run proven R4 path
        hipLaunchKernelGGL(k0_backbone, dim3(1),  dim3(256), 0, stream,
                           positions, grid, W1, b1, W2, b2, h2g_ws, win_ws);
        hipLaunchKernelGGL(k1_gf,      dim3(8),  dim3(256), 0, stream,
                           W3, b3, h2g_ws, win_ws, gf_ws);
        hipLaunchKernelGGL(k2_tpart,   dim3(64), dim3(256), 0, stream,
                           Wn1, bn1, gf_ws, tpart_ws);
        hipLaunchKernelGGL(k3_agg,     dim3(8),  dim3(256), 0, stream,
                           Wn2, bn2, tpart_ws, agg_ws);
        hipLaunchKernelGGL(k4_heads,   dim3(16), dim3(256), 0, stream,
                           Wh1, bh1, agg_ws, h1h_ws);
        hipLaunchKernelGGL(k5_out,     dim3(1),  dim3(256), 0, stream,
                           Wh2, bh2, h1h_ws, out);
    }
}